// Round 1
// baseline (817.076 us; speedup 1.0000x reference)
//
#include <hip/hip_runtime.h>
#include <hip/hip_bf16.h>
#include <stdint.h>

typedef __bf16 bf16_t;
typedef bf16_t bf16x8 __attribute__((ext_vector_type(8)));
typedef bf16_t bf16x4 __attribute__((ext_vector_type(4)));
typedef float  f32x4  __attribute__((ext_vector_type(4)));

#define AS1(p) ((const __attribute__((address_space(1))) void*)(p))
#define AS3(p) ((__attribute__((address_space(3))) void*)(p))

static constexpr int B_ = 32, S_ = 1024, D_ = 1024, P_ = 4, F_ = 4096;
static constexpr int SPP = S_ / P_;          // 256 rows per (batch, phase) chunk
static constexpr int MP  = B_ * SPP;         // 8192 rows per phase-group

// ---- x: [B,S,D] f32 -> xg: [P][MP][D] bf16 (phase-grouped, contiguous) ----
__global__ void conv_x_kernel(const float* __restrict__ x, bf16_t* __restrict__ xg) {
  const int64_t n4 = (int64_t)B_ * S_ * D_ / 4;   // 8,388,608 float4 groups
  for (int64_t i = (int64_t)blockIdx.x * blockDim.x + threadIdx.x; i < n4;
       i += (int64_t)gridDim.x * blockDim.x) {
    int64_t e = i << 2;                       // element index
    int d = (int)(e & (D_ - 1));
    int s = (int)((e >> 10) & (S_ - 1));
    int b = (int)(e >> 20);
    int p = s >> 8;                           // contiguous partition: phase = s / 256
    int r = (b << 8) | (s & 255);             // row within phase-group
    const float4 v = ((const float4*)x)[i];
    bf16x4 o;
    o[0] = (bf16_t)v.x; o[1] = (bf16_t)v.y; o[2] = (bf16_t)v.z; o[3] = (bf16_t)v.w;
    *(bf16x4*)&xg[(((int64_t)p * MP + r) << 10) | d] = o;
  }
}

// ---- W: [P][K][N] f32 -> Wt: [P][N][K] bf16 (LDS-tiled transpose) ----
__global__ void conv_wt_kernel(const float* __restrict__ W, bf16_t* __restrict__ Wt,
                               int K, int N) {
  __shared__ bf16_t tile[32][33];
  const int p = blockIdx.z;
  const float* Wp = W + (int64_t)p * K * N;
  bf16_t* Wtp = Wt + (int64_t)p * K * N;
  const int n0 = blockIdx.x * 32, k0 = blockIdx.y * 32;
  const int tx = threadIdx.x & 31, ty = threadIdx.x >> 5;
  #pragma unroll
  for (int j = 0; j < 4; ++j) {
    int kr = ty + j * 8;
    tile[kr][tx] = (bf16_t)Wp[(int64_t)(k0 + kr) * N + n0 + tx];
  }
  __syncthreads();
  #pragma unroll
  for (int j = 0; j < 4; ++j) {
    int nr = ty + j * 8;
    Wtp[(int64_t)(n0 + nr) * K + k0 + tx] = tile[tx][nr];
  }
}

// ---- per-phase GEMM: C[M,N] = A[M,K] * Bt[N,K]^T (+bias, opt ReLU) ----
// m97 structure: 128x128 tile, BK=32, 4 waves (2x2 of 64x64), global_load_lds w=16.
template<bool RELU, bool OUT_BF16>
__global__ void ffgemm_kernel(const bf16_t* __restrict__ A, const bf16_t* __restrict__ Bt,
                              const float* __restrict__ bias, void* __restrict__ outv,
                              int M, int N, int K) {
  constexpr int BM = 128, BN = 128, BK = 32;
  __shared__ bf16_t As[BM * BK];   // 8 KiB, linear [128][32]
  __shared__ bf16_t Bs[BN * BK];   // 8 KiB, linear [128][32] (rows = C columns)
  const int p = blockIdx.z;
  A    += (int64_t)p * M * K;
  Bt   += (int64_t)p * N * K;
  bias += p * N;
  const int tile_n = blockIdx.x * BN, tile_m = blockIdx.y * BM;
  const int t = threadIdx.x, lane = t & 63, w = t >> 6;
  const int wm = w >> 1, wn = w & 1;
  const bf16_t* Ab = A  + (int64_t)tile_m * K;
  const bf16_t* Bb = Bt + (int64_t)tile_n * K;
  const int srow = t >> 2, scol = (t & 3) * 8;   // staging: 16B per thread per inst
  const int koff = (lane >> 4) * 8;              // A/B fragment k-offset
  const int fr   = lane & 15;                    // fragment row (A) / col (B)
  f32x4 acc[4][4] = {};
  for (int k0 = 0; k0 < K; k0 += BK) {
    #pragma unroll
    for (int i = 0; i < 2; ++i) {
      __builtin_amdgcn_global_load_lds(AS1(Ab + (int64_t)(srow + i * 64) * K + k0 + scol),
                                       AS3(As + i * 2048 + t * 8), 16, 0, 0);
      __builtin_amdgcn_global_load_lds(AS1(Bb + (int64_t)(srow + i * 64) * K + k0 + scol),
                                       AS3(Bs + i * 2048 + t * 8), 16, 0, 0);
    }
    __syncthreads();   // compiler emits s_waitcnt vmcnt(0) before s_barrier
    bf16x8 af[4], bfr[4];
    #pragma unroll
    for (int m = 0; m < 4; ++m)
      af[m] = *(const bf16x8*)&As[(wm * 64 + m * 16 + fr) * BK + koff];
    #pragma unroll
    for (int n = 0; n < 4; ++n)
      bfr[n] = *(const bf16x8*)&Bs[(wn * 64 + n * 16 + fr) * BK + koff];
    #pragma unroll
    for (int m = 0; m < 4; ++m)
      #pragma unroll
      for (int n = 0; n < 4; ++n)
        acc[m][n] = __builtin_amdgcn_mfma_f32_16x16x32_bf16(af[m], bfr[n], acc[m][n], 0, 0, 0);
    __syncthreads();
  }
  // epilogue: C/D layout col=lane&15, row=(lane>>4)*4+j  [m89-verified]
  const int hi = lane >> 4;
  float bv[4];
  #pragma unroll
  for (int n = 0; n < 4; ++n) bv[n] = bias[tile_n + wn * 64 + n * 16 + fr];
  if (OUT_BF16) {
    bf16_t* out = (bf16_t*)outv + (int64_t)p * M * N;
    #pragma unroll
    for (int m = 0; m < 4; ++m) {
      #pragma unroll
      for (int j = 0; j < 4; ++j) {
        int row = tile_m + wm * 64 + m * 16 + hi * 4 + j;
        #pragma unroll
        for (int n = 0; n < 4; ++n) {
          int col = tile_n + wn * 64 + n * 16 + fr;
          float v = acc[m][n][j] + bv[n];
          if (RELU) v = fmaxf(v, 0.0f);
          out[(int64_t)row * N + col] = (bf16_t)v;
        }
      }
    }
  } else {
    // scatter back to y[B,S,D] f32: phase-local row r -> global row (r/256)*S + p*256 + r%256
    float* out = (float*)outv;
    #pragma unroll
    for (int m = 0; m < 4; ++m) {
      #pragma unroll
      for (int j = 0; j < 4; ++j) {
        int row = tile_m + wm * 64 + m * 16 + hi * 4 + j;
        int grow = ((row >> 8) << 10) + p * SPP + (row & 255);
        #pragma unroll
        for (int n = 0; n < 4; ++n) {
          int col = tile_n + wn * 64 + n * 16 + fr;
          out[(int64_t)grow * N + col] = acc[m][n][j] + bv[n];
        }
      }
    }
  }
}

extern "C" void kernel_launch(void* const* d_in, const int* in_sizes, int n_in,
                              void* d_out, int out_size, void* d_ws, size_t ws_size,
                              hipStream_t stream) {
  (void)in_sizes; (void)n_in; (void)out_size; (void)ws_size;
  const float* x  = (const float*)d_in[0];
  const float* W1 = (const float*)d_in[1];
  const float* b1 = (const float*)d_in[2];
  const float* W2 = (const float*)d_in[3];
  const float* b2 = (const float*)d_in[4];
  // d_in[5] = phases: unused — reference's branched path is the static
  // contiguous equal partition (reshape), independent of the phases values.
  float* y = (float*)d_out;

  char* ws = (char*)d_ws;
  bf16_t* xg = (bf16_t*)ws;                                   // 64 MiB  [P][8192][1024] bf16
  bf16_t* wt = (bf16_t*)(ws + (size_t)64 * 1024 * 1024);      // 32 MiB  [N][K] bf16 (W1t then W2t)
  bf16_t* h  = (bf16_t*)(ws + (size_t)96 * 1024 * 1024);      // 256 MiB [P][8192][4096] bf16
  // total ws use: 352 MiB

  conv_x_kernel<<<2048, 256, 0, stream>>>(x, xg);
  conv_wt_kernel<<<dim3(F_ / 32, D_ / 32, P_), 256, 0, stream>>>(W1, wt, D_, F_);
  ffgemm_kernel<true, true><<<dim3(F_ / 128, MP / 128, P_), 256, 0, stream>>>(
      xg, wt, b1, h, MP, F_, D_);
  conv_wt_kernel<<<dim3(D_ / 32, F_ / 32, P_), 256, 0, stream>>>(W2, wt, F_, D_);
  ffgemm_kernel<false, false><<<dim3(D_ / 128, MP / 128, P_), 256, 0, stream>>>(
      h, wt, b2, y, MP, D_, F_);
}

// Round 2
// 579.037 us; speedup vs baseline: 1.4111x; 1.4111x over previous
//
#include <hip/hip_runtime.h>
#include <hip/hip_bf16.h>
#include <stdint.h>

typedef __bf16 bf16_t;
typedef bf16_t bf16x8 __attribute__((ext_vector_type(8)));
typedef bf16_t bf16x4 __attribute__((ext_vector_type(4)));
typedef float  f32x4  __attribute__((ext_vector_type(4)));

#define AS1(p) ((const __attribute__((address_space(1))) void*)(p))
#define AS3(p) ((__attribute__((address_space(3))) void*)(p))

static constexpr int B_ = 32, S_ = 1024, D_ = 1024, P_ = 4, F_ = 4096;
static constexpr int SPP = S_ / P_;          // 256 rows per (batch, phase) chunk
static constexpr int MP  = B_ * SPP;         // 8192 rows per phase-group

// ---- x: [B,S,D] f32 -> xg: [P][MP][D] bf16 (phase-grouped, contiguous) ----
__global__ void conv_x_kernel(const float* __restrict__ x, bf16_t* __restrict__ xg) {
  const int64_t n4 = (int64_t)B_ * S_ * D_ / 4;
  for (int64_t i = (int64_t)blockIdx.x * blockDim.x + threadIdx.x; i < n4;
       i += (int64_t)gridDim.x * blockDim.x) {
    int64_t e = i << 2;
    int d = (int)(e & (D_ - 1));
    int s = (int)((e >> 10) & (S_ - 1));
    int b = (int)(e >> 20);
    int p = s >> 8;
    int r = (b << 8) | (s & 255);
    const float4 v = ((const float4*)x)[i];
    bf16x4 o;
    o[0] = (bf16_t)v.x; o[1] = (bf16_t)v.y; o[2] = (bf16_t)v.z; o[3] = (bf16_t)v.w;
    *(bf16x4*)&xg[(((int64_t)p * MP + r) << 10) | d] = o;
  }
}

// ---- W: [P][K][N] f32 -> Wt: [P][N][K] bf16 (LDS-tiled transpose) ----
__global__ void conv_wt_kernel(const float* __restrict__ W, bf16_t* __restrict__ Wt,
                               int K, int N) {
  __shared__ bf16_t tile[32][33];
  const int p = blockIdx.z;
  const float* Wp = W + (int64_t)p * K * N;
  bf16_t* Wtp = Wt + (int64_t)p * K * N;
  const int n0 = blockIdx.x * 32, k0 = blockIdx.y * 32;
  const int tx = threadIdx.x & 31, ty = threadIdx.x >> 5;
  #pragma unroll
  for (int j = 0; j < 4; ++j) {
    int kr = ty + j * 8;
    tile[kr][tx] = (bf16_t)Wp[(int64_t)(k0 + kr) * N + n0 + tx];
  }
  __syncthreads();
  #pragma unroll
  for (int j = 0; j < 4; ++j) {
    int nr = ty + j * 8;
    Wtp[(int64_t)(n0 + nr) * K + k0 + tx] = tile[tx][nr];
  }
}

// ================= 256x256 8-phase GEMM (T1+T2+T3+T4+T5) ==================
// C[M,N] = A[M,K] * Bt[N,K]^T (+bias, opt ReLU). BM=BN=256, BK=64, 8 waves.
// LDS 128 KiB: A bufs [0,64K), B bufs [64K,128K); each tile 256x64 bf16 = 32K.
// Swizzle: logical (row, colbyte cb) stored at row*128 + (cb ^ ((row&7)<<4)).
// global_load_lds writes LINEAR LDS; the inverse perm is applied to the
// global SOURCE column (rule #21: both-sides-or-neither).

__device__ __forceinline__ bf16x8 ldsfrag(const char* region, int row, int cb) {
  return *(const bf16x8*)(region + row * 128 + (cb ^ ((row & 7) << 4)));
}

template<int LDK>
__device__ __forceinline__ void stage_half(const bf16_t* gsrc, char* ldsreg, int t) {
  #pragma unroll
  for (int j = 0; j < 2; ++j) {
    const int idx = j * 512 + t;          // 1024 x 16B = 128 rows x 64 cols bf16
    const int row = idx >> 3;
    const int cb  = ((idx & 7) << 4) ^ ((row & 7) << 4);   // inverse-swizzled src col
    __builtin_amdgcn_global_load_lds(AS1((const char*)(gsrc + (int64_t)row * LDK) + cb),
                                     AS3(ldsreg + idx * 16), 16, 0, 0);
  }
}

#define MFMA_QUAD(AF, BF, MO, NO) \
  do { _Pragma("unroll") for (int m_ = 0; m_ < 4; ++m_) \
       _Pragma("unroll") for (int n_ = 0; n_ < 2; ++n_) \
       _Pragma("unroll") for (int k_ = 0; k_ < 2; ++k_) \
         acc[(MO) + m_][(NO) + n_] = __builtin_amdgcn_mfma_f32_16x16x32_bf16( \
             AF[m_][k_], BF[n_][k_], acc[(MO) + m_][(NO) + n_], 0, 0, 0); } while (0)

#define READ_A4(DST, REG, MO) \
  do { _Pragma("unroll") for (int m_ = 0; m_ < 4; ++m_) \
       _Pragma("unroll") for (int k_ = 0; k_ < 2; ++k_) \
         DST[m_][k_] = ldsfrag(REG, wm * 128 + ((MO) + m_) * 16 + fr, k_ * 64 + hi * 16); } while (0)

#define READ_B2(DST, REG, NO) \
  do { _Pragma("unroll") for (int n_ = 0; n_ < 2; ++n_) \
       _Pragma("unroll") for (int k_ = 0; k_ < 2; ++k_) \
         DST[n_][k_] = ldsfrag(REG, wn * 64 + ((NO) + n_) * 16 + fr, k_ * 64 + hi * 16); } while (0)

#define BAR()   __builtin_amdgcn_s_barrier()
#define SBAR()  __builtin_amdgcn_sched_barrier(0)
#define PRIO(x) __builtin_amdgcn_s_setprio(x)
#define VMCNT6() asm volatile("s_waitcnt vmcnt(6)" ::: "memory")
#define VMCNT0() asm volatile("s_waitcnt vmcnt(0)" ::: "memory")

template<bool RELU, bool OUT_BF16, int KK, int NN>
__global__ __launch_bounds__(512, 2)
void ffgemm8_kernel(const bf16_t* __restrict__ A, const bf16_t* __restrict__ Bt,
                    const float* __restrict__ bias, void* __restrict__ outv, int M) {
  static_assert(KK % 128 == 0, "need even number of 64-wide K tiles");
  __shared__ __align__(16) char smem[131072];
  char* const At0 = smem;
  char* const At1 = smem + 32768;
  char* const Bs0 = smem + 65536;
  char* const Bs1 = smem + 98304;

  const int t = threadIdx.x, lane = t & 63, w = t >> 6;
  const int wm = w >> 2, wn = w & 3;          // 2M x 4N wave grid
  const int fr = lane & 15, hi = lane >> 4;

  // T1: bijective XCD swizzle over the flattened grid (nwg % 8 == 0 here)
  const int gx = gridDim.x, gy = gridDim.y;
  const int nwg = gx * gy * (int)gridDim.z;
  const int id  = ((int)blockIdx.z * gy + (int)blockIdx.y) * gx + (int)blockIdx.x;
  const int swz = (id & 7) * (nwg >> 3) + (id >> 3);
  const int bx = swz % gx;
  const int rem = swz / gx;
  const int by = rem % gy;
  const int p  = rem / gy;

  const int tile_m = by * 256, tile_n = bx * 256;
  const bf16_t* Ab = A  + (int64_t)p * M  * KK + (int64_t)tile_m * KK;
  const bf16_t* Bb = Bt + (int64_t)p * NN * KK + (int64_t)tile_n * KK;
  const float* biasp = bias + (int64_t)p * NN;

  f32x4 acc[8][4] = {};
  constexpr int NT = KK / 64, NI = NT / 2;

  // ---- prologue: tile0 -> buf0 (A0,A1,B0,B1); tile1 -> buf1 (B0,B1,A0) ----
  stage_half<KK>(Ab,                        At0,          t);
  stage_half<KK>(Ab + (int64_t)128 * KK,    At0 + 16384,  t);
  stage_half<KK>(Bb,                        Bs0,          t);
  stage_half<KK>(Bb + (int64_t)128 * KK,    Bs0 + 16384,  t);
  stage_half<KK>(Bb + 64,                   Bs1,          t);
  stage_half<KK>(Bb + (int64_t)128 * KK + 64, Bs1 + 16384, t);
  stage_half<KK>(Ab + 64,                   At1,          t);
  VMCNT6();          // tile0's 8 loads landed; tile1's 3 halves in flight
  BAR(); SBAR();

  for (int i = 0; i < NI; ++i) {
    const int k0 = i * 128;                  // tile 2i @ k0, tile 2i+1 @ k0+64
    const bool more = (i < NI - 1);
    bf16x8 a0[4][2], a1[4][2], b0[2][2], b1[2][2];

    // ph1: quad(0,0) tile2i | stage A1(tile 2i+1)->buf1
    READ_A4(a0, At0, 0); READ_B2(b0, Bs0, 0);
    stage_half<KK>(Ab + (int64_t)128 * KK + (k0 + 64), At1 + 16384, t);
    BAR(); PRIO(1); MFMA_QUAD(a0, b0, 0, 0); PRIO(0); BAR();
    // ph2: quad(0,1) | stage B0(tile 2i+2)->buf0
    READ_B2(b1, Bs0, 2);
    if (more) stage_half<KK>(Bb + (k0 + 128), Bs0, t);
    BAR(); PRIO(1); MFMA_QUAD(a0, b1, 0, 2); PRIO(0); BAR();
    // ph3: quad(1,0) | stage B1(tile 2i+2)
    READ_A4(a1, At0, 4);
    if (more) stage_half<KK>(Bb + (int64_t)128 * KK + (k0 + 128), Bs0 + 16384, t);
    BAR(); PRIO(1); MFMA_QUAD(a1, b0, 4, 0); PRIO(0); BAR();
    // ph4: quad(1,1) | stage A0(tile 2i+2) | counted drain
    if (more) stage_half<KK>(Ab + (k0 + 128), At0, t);
    BAR(); PRIO(1); MFMA_QUAD(a1, b1, 4, 2); PRIO(0);
    if (more) VMCNT6(); else VMCNT0();
    BAR(); SBAR();

    // ph5: quad(0,0) tile2i+1 (buf1) | stage A1(tile 2i+2)->buf0
    READ_A4(a0, At1, 0); READ_B2(b0, Bs1, 0);
    if (more) stage_half<KK>(Ab + (int64_t)128 * KK + (k0 + 128), At0 + 16384, t);
    BAR(); PRIO(1); MFMA_QUAD(a0, b0, 0, 0); PRIO(0); BAR();
    // ph6: quad(0,1) | stage B0(tile 2i+3)->buf1
    READ_B2(b1, Bs1, 2);
    if (more) stage_half<KK>(Bb + (k0 + 192), Bs1, t);
    BAR(); PRIO(1); MFMA_QUAD(a0, b1, 0, 2); PRIO(0); BAR();
    // ph7: quad(1,0) | stage B1(tile 2i+3)
    READ_A4(a1, At1, 4);
    if (more) stage_half<KK>(Bb + (int64_t)128 * KK + (k0 + 192), Bs1 + 16384, t);
    BAR(); PRIO(1); MFMA_QUAD(a1, b0, 4, 0); PRIO(0); BAR();
    // ph8: quad(1,1) | stage A0(tile 2i+3) | counted drain
    if (more) stage_half<KK>(Ab + (k0 + 192), At1, t);
    BAR(); PRIO(1); MFMA_QUAD(a1, b1, 4, 2); PRIO(0);
    if (more) VMCNT6(); else VMCNT0();
    BAR(); SBAR();
  }

  // ---- epilogue: C/D layout col=lane&15, row=(lane>>4)*4+j ----
  float bv[4];
  #pragma unroll
  for (int n = 0; n < 4; ++n) bv[n] = biasp[tile_n + wn * 64 + n * 16 + fr];
  if (OUT_BF16) {
    bf16_t* out = (bf16_t*)outv + (int64_t)p * M * NN;
    #pragma unroll
    for (int m = 0; m < 8; ++m)
      #pragma unroll
      for (int j = 0; j < 4; ++j) {
        const int row = tile_m + wm * 128 + m * 16 + hi * 4 + j;
        #pragma unroll
        for (int n = 0; n < 4; ++n) {
          const int col = tile_n + wn * 64 + n * 16 + fr;
          float v = acc[m][n][j] + bv[n];
          if (RELU) v = fmaxf(v, 0.0f);
          out[(int64_t)row * NN + col] = (bf16_t)v;
        }
      }
  } else {
    float* out = (float*)outv;
    #pragma unroll
    for (int m = 0; m < 8; ++m)
      #pragma unroll
      for (int j = 0; j < 4; ++j) {
        const int row = tile_m + wm * 128 + m * 16 + hi * 4 + j;
        const int grow = ((row >> 8) << 10) + p * SPP + (row & 255);
        #pragma unroll
        for (int n = 0; n < 4; ++n) {
          const int col = tile_n + wn * 64 + n * 16 + fr;
          out[(int64_t)grow * NN + col] = acc[m][n][j] + bv[n];
        }
      }
  }
}

extern "C" void kernel_launch(void* const* d_in, const int* in_sizes, int n_in,
                              void* d_out, int out_size, void* d_ws, size_t ws_size,
                              hipStream_t stream) {
  (void)in_sizes; (void)n_in; (void)out_size; (void)ws_size;
  const float* x  = (const float*)d_in[0];
  const float* W1 = (const float*)d_in[1];
  const float* b1 = (const float*)d_in[2];
  const float* W2 = (const float*)d_in[3];
  const float* b2 = (const float*)d_in[4];
  // d_in[5] = phases: unused — static contiguous equal partition (reshape).
  float* y = (float*)d_out;

  char* ws = (char*)d_ws;
  bf16_t* xg = (bf16_t*)ws;                                   // 64 MiB  [P][8192][1024] bf16
  bf16_t* wt = (bf16_t*)(ws + (size_t)64 * 1024 * 1024);      // 32 MiB  [N][K] bf16 (W1t then W2t)
  bf16_t* h  = (bf16_t*)(ws + (size_t)96 * 1024 * 1024);      // 256 MiB [P][8192][4096] bf16

  conv_x_kernel<<<2048, 256, 0, stream>>>(x, xg);
  conv_wt_kernel<<<dim3(F_ / 32, D_ / 32, P_), 256, 0, stream>>>(W1, wt, D_, F_);
  ffgemm8_kernel<true, true, 1024, 4096><<<dim3(F_ / 256, MP / 256, P_), 512, 0, stream>>>(
      xg, wt, b1, h, MP);
  conv_wt_kernel<<<dim3(D_ / 32, F_ / 32, P_), 256, 0, stream>>>(W2, wt, F_, D_);
  ffgemm8_kernel<false, false, 4096, 1024><<<dim3(D_ / 256, MP / 256, P_), 512, 0, stream>>>(
      h, wt, b2, y, MP);
}

// Round 3
// 575.095 us; speedup vs baseline: 1.4208x; 1.0069x over previous
//
#include <hip/hip_runtime.h>
#include <hip/hip_bf16.h>
#include <stdint.h>

typedef __bf16 bf16_t;
typedef bf16_t bf16x8 __attribute__((ext_vector_type(8)));
typedef bf16_t bf16x4 __attribute__((ext_vector_type(4)));
typedef float  f32x4  __attribute__((ext_vector_type(4)));

#define AS1(p) ((const __attribute__((address_space(1))) void*)(p))
#define AS3(p) ((__attribute__((address_space(3))) void*)(p))

static constexpr int B_ = 32, S_ = 1024, D_ = 1024, P_ = 4, F_ = 4096;
static constexpr int SPP = S_ / P_;          // 256 rows per (batch, phase) chunk
static constexpr int MP  = B_ * SPP;         // 8192 rows per phase-group

// ---- x: [B,S,D] f32 -> xg: [P][MP][D] bf16 (phase-grouped, contiguous) ----
__global__ void conv_x_kernel(const float* __restrict__ x, bf16_t* __restrict__ xg) {
  const int64_t n4 = (int64_t)B_ * S_ * D_ / 4;
  for (int64_t i = (int64_t)blockIdx.x * blockDim.x + threadIdx.x; i < n4;
       i += (int64_t)gridDim.x * blockDim.x) {
    int64_t e = i << 2;
    int d = (int)(e & (D_ - 1));
    int s = (int)((e >> 10) & (S_ - 1));
    int b = (int)(e >> 20);
    int p = s >> 8;
    int r = (b << 8) | (s & 255);
    const float4 v = ((const float4*)x)[i];
    bf16x4 o;
    o[0] = (bf16_t)v.x; o[1] = (bf16_t)v.y; o[2] = (bf16_t)v.z; o[3] = (bf16_t)v.w;
    *(bf16x4*)&xg[(((int64_t)p * MP + r) << 10) | d] = o;
  }
}

// ---- W: [P][K][N] f32 -> Wt: [P][N][K] bf16 (LDS-tiled transpose) ----
__global__ void conv_wt_kernel(const float* __restrict__ W, bf16_t* __restrict__ Wt,
                               int K, int N) {
  __shared__ bf16_t tile[32][33];
  const int p = blockIdx.z;
  const float* Wp = W + (int64_t)p * K * N;
  bf16_t* Wtp = Wt + (int64_t)p * K * N;
  const int n0 = blockIdx.x * 32, k0 = blockIdx.y * 32;
  const int tx = threadIdx.x & 31, ty = threadIdx.x >> 5;
  #pragma unroll
  for (int j = 0; j < 4; ++j) {
    int kr = ty + j * 8;
    tile[kr][tx] = (bf16_t)Wp[(int64_t)(k0 + kr) * N + n0 + tx];
  }
  __syncthreads();
  #pragma unroll
  for (int j = 0; j < 4; ++j) {
    int nr = ty + j * 8;
    Wtp[(int64_t)(n0 + nr) * K + k0 + tx] = tile[tx][nr];
  }
}

// ================= 256x256 8-phase GEMM (T1+T2+T3+T4+T5) ==================
// C[M,N] = A[M,K] * Bt[N,K]^T (+bias, opt ReLU). BM=BN=256, BK=64, 8 waves.
// LDS 128 KiB: At0 At1 Bs0 Bs1, each a 256x64 bf16 tile (32 KiB, two halves).
// Swizzle: logical (row, colbyte cb) stored at row*128 + (cb ^ ((row&7)<<4));
// global_load_lds dest stays LINEAR, inverse perm applied to global source.
// Stage schedule (WAR-safe: every stage is issued strictly after the closing
// barrier of the phase containing the destination buffer's last ds_read):
//   ph1: A1(t+1)->At1b   [At1b last read prev ph7]
//   ph3: B0,B1(t+2)->Bs0 [Bs0 last read ph2]
//   ph4: A0(t+2)->At0a   [At0a last read ph3]; vmcnt(6) retires tile t+1
//   ph5: A1(t+2)->At0b   [At0b last read ph3]
//   ph7: B0,B1(t+3)->Bs1 [Bs1 last read ph6]
//   ph8: A0(t+3)->At1a   [At1a last read ph7]; vmcnt(6) retires tile t+2

__device__ __forceinline__ bf16x8 ldsfrag(const char* region, int row, int cb) {
  return *(const bf16x8*)(region + row * 128 + (cb ^ ((row & 7) << 4)));
}

template<int LDK>
__device__ __forceinline__ void stage_half(const bf16_t* gsrc, char* ldsreg, int t) {
  #pragma unroll
  for (int j = 0; j < 2; ++j) {
    const int idx = j * 512 + t;          // 1024 x 16B = 128 rows x 64 cols bf16
    const int row = idx >> 3;
    const int cb  = ((idx & 7) << 4) ^ ((row & 7) << 4);   // inverse-swizzled src col
    __builtin_amdgcn_global_load_lds(AS1((const char*)(gsrc + (int64_t)row * LDK) + cb),
                                     AS3(ldsreg + idx * 16), 16, 0, 0);
  }
}

#define MFMA_QUAD(AF, BF, MO, NO) \
  do { _Pragma("unroll") for (int m_ = 0; m_ < 4; ++m_) \
       _Pragma("unroll") for (int n_ = 0; n_ < 2; ++n_) \
       _Pragma("unroll") for (int k_ = 0; k_ < 2; ++k_) \
         acc[(MO) + m_][(NO) + n_] = __builtin_amdgcn_mfma_f32_16x16x32_bf16( \
             AF[m_][k_], BF[n_][k_], acc[(MO) + m_][(NO) + n_], 0, 0, 0); } while (0)

#define READ_A4(DST, REG, MO) \
  do { _Pragma("unroll") for (int m_ = 0; m_ < 4; ++m_) \
       _Pragma("unroll") for (int k_ = 0; k_ < 2; ++k_) \
         DST[m_][k_] = ldsfrag(REG, wm * 128 + ((MO) + m_) * 16 + fr, k_ * 64 + hi * 16); } while (0)

#define READ_B2(DST, REG, NO) \
  do { _Pragma("unroll") for (int n_ = 0; n_ < 2; ++n_) \
       _Pragma("unroll") for (int k_ = 0; k_ < 2; ++k_) \
         DST[n_][k_] = ldsfrag(REG, wn * 64 + ((NO) + n_) * 16 + fr, k_ * 64 + hi * 16); } while (0)

#define BAR()   __builtin_amdgcn_s_barrier()
#define SBAR()  __builtin_amdgcn_sched_barrier(0)
#define PRIO(x) __builtin_amdgcn_s_setprio(x)
#define VMCNT6() asm volatile("s_waitcnt vmcnt(6)" ::: "memory")
#define VMCNT0() asm volatile("s_waitcnt vmcnt(0)" ::: "memory")
#define LGKM0() do { asm volatile("s_waitcnt lgkmcnt(0)" ::: "memory"); SBAR(); } while (0)
#define LGKM8() asm volatile("s_waitcnt lgkmcnt(8)" ::: "memory")

template<bool RELU, bool OUT_BF16, int KK, int NN>
__global__ __launch_bounds__(512, 2)
void ffgemm8_kernel(const bf16_t* __restrict__ A, const bf16_t* __restrict__ Bt,
                    const float* __restrict__ bias, void* __restrict__ outv, int M) {
  static_assert(KK % 128 == 0, "need even number of 64-wide K tiles");
  __shared__ __align__(16) char smem[131072];
  char* const At0 = smem;
  char* const At1 = smem + 32768;
  char* const Bs0 = smem + 65536;
  char* const Bs1 = smem + 98304;

  const int t = threadIdx.x, lane = t & 63, w = t >> 6;
  const int wm = w >> 2, wn = w & 3;          // 2M x 4N wave grid
  const int fr = lane & 15, hi = lane >> 4;

  // T1: bijective XCD swizzle (nwg % 8 == 0) + 4-row supertile banding for L2
  const int gx = gridDim.x, gy = gridDim.y;
  const int nwg = gx * gy * (int)gridDim.z;
  const int id  = ((int)blockIdx.z * gy + (int)blockIdx.y) * gx + (int)blockIdx.x;
  const int swz = (id & 7) * (nwg >> 3) + (id >> 3);
  const int per_p = gx * gy;
  const int p  = swz / per_p;
  const int q  = swz % per_p;
  // band of 4 rows, column-major inside the band (gy % 4 == 0)
  const int band = q / (gx * 4), qq = q % (gx * 4);
  const int bx = qq >> 2, by = band * 4 + (qq & 3);

  const int tile_m = by * 256, tile_n = bx * 256;
  const bf16_t* Ab = A  + (int64_t)p * M  * KK + (int64_t)tile_m * KK;
  const bf16_t* Bb = Bt + (int64_t)p * NN * KK + (int64_t)tile_n * KK;
  const float* biasp = bias + (int64_t)p * NN;

  f32x4 acc[8][4] = {};
  constexpr int NI = KK / 128;

  // ---- prologue: tile0 (A0,A1,B0,B1) -> buf0; tile1 (B0,B1,A0) -> buf1 ----
  stage_half<KK>(Ab,                          At0,          t);
  stage_half<KK>(Ab + (int64_t)128 * KK,      At0 + 16384,  t);
  stage_half<KK>(Bb,                          Bs0,          t);
  stage_half<KK>(Bb + (int64_t)128 * KK,      Bs0 + 16384,  t);
  stage_half<KK>(Bb + 64,                     Bs1,          t);
  stage_half<KK>(Bb + (int64_t)128 * KK + 64, Bs1 + 16384,  t);
  stage_half<KK>(Ab + 64,                     At1,          t);
  VMCNT6();          // tile0's 8 loads landed; tile1's B0,B1,A0 in flight
  BAR(); SBAR();

  for (int i = 0; i < NI; ++i) {
    const int k0 = i * 128;                  // tile 2i @ k0, tile 2i+1 @ k0+64
    const bool more = (i < NI - 1);
    bf16x8 a0[4][2], a1[4][2], b0[2][2], b1[2][2];

    // ph1: quad(0,0) tile2i | stage A1(t2i+1)->At1b
    READ_A4(a0, At0, 0); READ_B2(b0, Bs0, 0);
    stage_half<KK>(Ab + (int64_t)128 * KK + (k0 + 64), At1 + 16384, t);
    LGKM8(); BAR(); LGKM0(); PRIO(1); MFMA_QUAD(a0, b0, 0, 0); PRIO(0); BAR();
    // ph2: quad(0,1) | no stage (Bs0 still being read)
    READ_B2(b1, Bs0, 2);
    BAR(); LGKM0(); PRIO(1); MFMA_QUAD(a0, b1, 0, 2); PRIO(0); BAR();
    // ph3: quad(1,0) | stage B0,B1(t2i+2)->Bs0
    READ_A4(a1, At0, 4);
    if (more) { stage_half<KK>(Bb + (k0 + 128), Bs0, t);
                stage_half<KK>(Bb + (int64_t)128 * KK + (k0 + 128), Bs0 + 16384, t); }
    BAR(); LGKM0(); PRIO(1); MFMA_QUAD(a1, b0, 4, 0); PRIO(0); BAR();
    // ph4: quad(1,1) | stage A0(t2i+2)->At0a | retire tile 2i+1
    if (more) stage_half<KK>(Ab + (k0 + 128), At0, t);
    BAR(); LGKM0(); PRIO(1); MFMA_QUAD(a1, b1, 4, 2); PRIO(0);
    if (more) VMCNT6(); else VMCNT0();
    BAR(); SBAR();

    // ph5: quad(0,0) tile2i+1 | stage A1(t2i+2)->At0b
    READ_A4(a0, At1, 0); READ_B2(b0, Bs1, 0);
    if (more) stage_half<KK>(Ab + (int64_t)128 * KK + (k0 + 128), At0 + 16384, t);
    LGKM8(); BAR(); LGKM0(); PRIO(1); MFMA_QUAD(a0, b0, 0, 0); PRIO(0); BAR();
    // ph6: quad(0,1) | no stage (Bs1 still being read)
    READ_B2(b1, Bs1, 2);
    BAR(); LGKM0(); PRIO(1); MFMA_QUAD(a0, b1, 0, 2); PRIO(0); BAR();
    // ph7: quad(1,0) | stage B0,B1(t2i+3)->Bs1
    READ_A4(a1, At1, 4);
    if (more) { stage_half<KK>(Bb + (k0 + 192), Bs1, t);
                stage_half<KK>(Bb + (int64_t)128 * KK + (k0 + 192), Bs1 + 16384, t); }
    BAR(); LGKM0(); PRIO(1); MFMA_QUAD(a1, b0, 4, 0); PRIO(0); BAR();
    // ph8: quad(1,1) | stage A0(t2i+3)->At1a | retire tile 2i+2
    if (more) stage_half<KK>(Ab + (k0 + 192), At1, t);
    BAR(); LGKM0(); PRIO(1); MFMA_QUAD(a1, b1, 4, 2); PRIO(0);
    if (more) VMCNT6(); else VMCNT0();
    BAR(); SBAR();
  }

  // ---- epilogue: C/D layout col=lane&15, row=(lane>>4)*4+j ----
  float bv[4];
  #pragma unroll
  for (int n = 0; n < 4; ++n) bv[n] = biasp[tile_n + wn * 64 + n * 16 + fr];
  if (OUT_BF16) {
    bf16_t* out = (bf16_t*)outv + (int64_t)p * M * NN;
    #pragma unroll
    for (int m = 0; m < 8; ++m)
      #pragma unroll
      for (int j = 0; j < 4; ++j) {
        const int row = tile_m + wm * 128 + m * 16 + hi * 4 + j;
        #pragma unroll
        for (int n = 0; n < 4; ++n) {
          const int col = tile_n + wn * 64 + n * 16 + fr;
          float v = acc[m][n][j] + bv[n];
          if (RELU) v = fmaxf(v, 0.0f);
          out[(int64_t)row * NN + col] = (bf16_t)v;
        }
      }
  } else {
    float* out = (float*)outv;
    #pragma unroll
    for (int m = 0; m < 8; ++m)
      #pragma unroll
      for (int j = 0; j < 4; ++j) {
        const int row = tile_m + wm * 128 + m * 16 + hi * 4 + j;
        const int grow = ((row >> 8) << 10) + p * SPP + (row & 255);
        #pragma unroll
        for (int n = 0; n < 4; ++n) {
          const int col = tile_n + wn * 64 + n * 16 + fr;
          out[(int64_t)grow * NN + col] = acc[m][n][j] + bv[n];
        }
      }
  }
}

extern "C" void kernel_launch(void* const* d_in, const int* in_sizes, int n_in,
                              void* d_out, int out_size, void* d_ws, size_t ws_size,
                              hipStream_t stream) {
  (void)in_sizes; (void)n_in; (void)out_size; (void)ws_size;
  const float* x  = (const float*)d_in[0];
  const float* W1 = (const float*)d_in[1];
  const float* b1 = (const float*)d_in[2];
  const float* W2 = (const float*)d_in[3];
  const float* b2 = (const float*)d_in[4];
  // d_in[5] = phases: unused — static contiguous equal partition (reshape).
  float* y = (float*)d_out;

  char* ws = (char*)d_ws;
  bf16_t* xg = (bf16_t*)ws;                                   // 64 MiB  [P][8192][1024] bf16
  bf16_t* wt = (bf16_t*)(ws + (size_t)64 * 1024 * 1024);      // 32 MiB  [N][K] bf16 (W1t then W2t)
  bf16_t* h  = (bf16_t*)(ws + (size_t)96 * 1024 * 1024);      // 256 MiB [P][8192][4096] bf16

  conv_x_kernel<<<2048, 256, 0, stream>>>(x, xg);
  conv_wt_kernel<<<dim3(F_ / 32, D_ / 32, P_), 256, 0, stream>>>(W1, wt, D_, F_);
  ffgemm8_kernel<true, true, 1024, 4096><<<dim3(F_ / 256, MP / 256, P_), 512, 0, stream>>>(
      xg, wt, b1, h, MP);
  conv_wt_kernel<<<dim3(D_ / 32, F_ / 32, P_), 256, 0, stream>>>(W2, wt, F_, D_);
  ffgemm8_kernel<false, false, 4096, 1024><<<dim3(D_ / 256, MP / 256, P_), 512, 0, stream>>>(
      h, wt, b2, y, MP);
}